// Round 11
// baseline (123.008 us; speedup 1.0000x reference)
//
#include <hip/hip_runtime.h>
#include <hip/hip_bf16.h>

typedef __attribute__((ext_vector_type(4))) float f32x4;
typedef __attribute__((ext_vector_type(8))) __bf16 bf16x8;

#define NCTX 8192
#define DH 128
#define ROWE 4096                    /* floats between consecutive positions */
#define SC2 0.12751705766482797f     /* (1/sqrt(128)) * log2(e) */
#define KSTR 136                     /* bf16 row stride in staged buffers */
#define PSTR 40                      /* P lds row stride (shorts) */
#define OSTR 132                     /* O-bounce row stride (floats) */
#define BUFS (32*KSTR)               /* shorts per 8.5KB buffer */

__device__ __forceinline__ unsigned f2bf(float x) {
  union { float f; unsigned u; } un; un.f = x;
  return (un.u + 0x7FFFu + ((un.u >> 16) & 1u)) >> 16;   // RNE f32->bf16 bits
}
__device__ __forceinline__ unsigned pk2(float a, float b) {
  float2 t; t.x = a; t.y = b;
  union { __hip_bfloat162 h; unsigned u; } un;
  un.h = __float22bfloat162_rn(t);
  return un.u;
}

// Stage one 4096-float global row -> LDS bf16 [32][KSTR], fully coalesced.
// NT=true: nontemporal loads (stream-once data, don't pollute L2/L3).
template<bool NT>
__device__ __forceinline__ void stage_row(const float* __restrict__ src,
                                          unsigned short* dst, int lane) {
  const int jb = lane >> 5, d = 4 * (lane & 31);
#pragma unroll
  for (int half = 0; half < 2; ++half) {
    f32x4 x[8];
#pragma unroll
    for (int ch = 0; ch < 8; ++ch) {
      const f32x4* p = reinterpret_cast<const f32x4*>(src + 4*lane + 256*(half*8 + ch));
      x[ch] = NT ? __builtin_nontemporal_load(p) : *p;
    }
#pragma unroll
    for (int ch = 0; ch < 8; ++ch) {
      const int j = jb + 2*(half*8 + ch);       // head row 0..31
      uint2 wv;
      wv.x = pk2(x[ch][0], x[ch][1]);
      wv.y = pk2(x[ch][2], x[ch][3]);
      *reinterpret_cast<uint2*>(&dst[j*KSTR + d]) = wv;
    }
  }
}

// One wave per position: 32(heads) x 32(heads) attention, d=128. Branchless:
// every wave stages Q (NT), K (row r, L2-hot for 75% of waves), V (early-issue
// two-half split hidden under QK-MFMA / softmax) through its single LDS buf.
// 4 bufs total (34816 B) -> 4 blocks/CU, 16 waves/CU, no __syncthreads.
__global__ __launch_bounds__(256, 4) void hda(
    const float* __restrict__ q, const float* __restrict__ kg,
    const float* __restrict__ v, float* __restrict__ out)
{
  extern __shared__ __align__(16) unsigned short lds[];   // 4 bufs of BUFS shorts

  const int tid  = threadIdx.x;
  const int w    = tid >> 6;
  const int lane = tid & 63;
  const int c = lane & 15;    // frag row/col index
  const int g = lane >> 4;    // lane group 0..3
  const int jb = lane >> 5, dcol = 4 * (lane & 31);   // staging lane map

  const int pos = blockIdx.x * 4 + w;     // 0..16383
  const int b = pos >> 13;
  const int s = pos & (NCTX - 1);
  const int r = min(4 * s, NCTX - 1);     // dilated + clamped K/V row

  const float* qb_ = q  + (size_t)b * NCTX * ROWE;
  const float* kb_ = kg + (size_t)b * NCTX * ROWE;
  const float* vb_ = v  + (size_t)b * NCTX * ROWE;
  float*       op  = out + ((size_t)b * NCTX + s) * ROWE;

  unsigned short* sb = lds + w * BUFS;    // per-wave buf (Q -> K -> V -> P -> O)

  // ---- Q: stage own row (nontemporal: read-once stream) -> frags
  stage_row<true>(qb_ + (size_t)s * ROWE, sb, lane);
  bf16x8 qa[2][4];
#pragma unroll
  for (int t = 0; t < 2; ++t)
#pragma unroll
    for (int ks = 0; ks < 4; ++ks)
      qa[t][ks] = *reinterpret_cast<const bf16x8*>(&sb[(t*16 + c)*KSTR + ks*32 + g*8]);

  // ---- K: stage row r (L2-hot when r==8191) -> frags
  stage_row<false>(kb_ + (size_t)r * ROWE, sb, lane);
  bf16x8 kf[2][4];
#pragma unroll
  for (int t = 0; t < 2; ++t)
#pragma unroll
    for (int ks = 0; ks < 4; ++ks)
      kf[t][ks] = *reinterpret_cast<const bf16x8*>(&sb[(t*16 + c)*KSTR + ks*32 + g*8]);

  // ---- V: issue half 1 (rows 0..15) to regs; latency hides under QK-MFMA
  const float* vsrc = vb_ + (size_t)r * ROWE;
  f32x4 vx[8];
#pragma unroll
  for (int ch = 0; ch < 8; ++ch)
    vx[ch] = *reinterpret_cast<const f32x4*>(vsrc + 4*lane + 256*ch);
  __builtin_amdgcn_sched_barrier(0);

  // ---- S = Q K^T over heads: 4 16x16 tiles, K-dim 128
  f32x4 S[2][2];
#pragma unroll
  for (int it = 0; it < 2; ++it)
#pragma unroll
    for (int jt = 0; jt < 2; ++jt) {
      f32x4 acc = (f32x4)0.0f;
#pragma unroll
      for (int ks = 0; ks < 4; ++ks)
        acc = __builtin_amdgcn_mfma_f32_16x16x32_bf16(qa[it][ks], kf[jt][ks], acc, 0, 0, 0);
      S[it][jt] = acc;
    }

  // ---- write V half 1 into sb (K frags consumed), issue half 2
#pragma unroll
  for (int ch = 0; ch < 8; ++ch) {
    uint2 wv;
    wv.x = pk2(vx[ch][0], vx[ch][1]);
    wv.y = pk2(vx[ch][2], vx[ch][3]);
    *reinterpret_cast<uint2*>(&sb[(jb + 2*ch)*KSTR + dcol]) = wv;
  }
#pragma unroll
  for (int ch = 0; ch < 8; ++ch)
    vx[ch] = *reinterpret_cast<const f32x4*>(vsrc + 4*lane + 256*(8 + ch));
  __builtin_amdgcn_sched_barrier(0);

  // D-layout: S[it][jt][rr] = S_full[it*16+g*4+rr][jt*16+c]
  // ---- softmax over 32 cols (no max-sub: scores ~N(0,1), exp2 arg small)
  float p[2][2][4], inv[2][4];
#pragma unroll
  for (int it = 0; it < 2; ++it) {
    float ls[4] = {0.f, 0.f, 0.f, 0.f};
#pragma unroll
    for (int jt = 0; jt < 2; ++jt)
#pragma unroll
      for (int rr = 0; rr < 4; ++rr) {
        float e = exp2f(S[it][jt][rr] * SC2);
        p[it][jt][rr] = e;
        ls[rr] += e;
      }
#pragma unroll
    for (int m = 1; m <= 8; m <<= 1)
#pragma unroll
      for (int rr = 0; rr < 4; ++rr)
        ls[rr] += __shfl_xor(ls[rr], m);
#pragma unroll
    for (int rr = 0; rr < 4; ++rr) inv[it][rr] = 1.0f / ls[rr];
  }

  // ---- write V half 2 (rows 16..31) into sb
#pragma unroll
  for (int ch = 0; ch < 8; ++ch) {
    uint2 wv;
    wv.x = pk2(vx[ch][0], vx[ch][1]);
    wv.y = pk2(vx[ch][2], vx[ch][3]);
    *reinterpret_cast<uint2*>(&sb[(jb + 2*(8 + ch))*KSTR + dcol]) = wv;
  }

  // ---- V B-frags via LDS u16 gather (before P overwrites sb)
  bf16x8 va[8];
#pragma unroll
  for (int dt = 0; dt < 8; ++dt) {
    unsigned t0 = sb[(g*8 + 0)*KSTR + dt*16 + c];
    unsigned t1 = sb[(g*8 + 1)*KSTR + dt*16 + c];
    unsigned t2 = sb[(g*8 + 2)*KSTR + dt*16 + c];
    unsigned t3 = sb[(g*8 + 3)*KSTR + dt*16 + c];
    unsigned t4 = sb[(g*8 + 4)*KSTR + dt*16 + c];
    unsigned t5 = sb[(g*8 + 5)*KSTR + dt*16 + c];
    unsigned t6 = sb[(g*8 + 6)*KSTR + dt*16 + c];
    unsigned t7 = sb[(g*8 + 7)*KSTR + dt*16 + c];
    union { unsigned u[4]; bf16x8 f; } un;
    un.u[0] = t0 | (t1 << 16); un.u[1] = t2 | (t3 << 16);
    un.u[2] = t4 | (t5 << 16); un.u[3] = t6 | (t7 << 16);
    va[dt] = un.f;
  }

  // ---- normalized P -> sb (row-major [i][j]), read back as A-frags
#pragma unroll
  for (int it = 0; it < 2; ++it)
#pragma unroll
    for (int jt = 0; jt < 2; ++jt)
#pragma unroll
      for (int rr = 0; rr < 4; ++rr)
        sb[(it*16 + g*4 + rr)*PSTR + jt*16 + c] =
            (unsigned short)f2bf(p[it][jt][rr] * inv[it][rr]);

  bf16x8 pa[2];   // lane holds P[it*16+c][g*8..+7]
  pa[0] = *reinterpret_cast<const bf16x8*>(&sb[c*PSTR + g*8]);
  pa[1] = *reinterpret_cast<const bf16x8*>(&sb[(16 + c)*PSTR + g*8]);

  // ---- O^T = V^T P^T per it-half; bounce through LDS for coalesced nt stores
  float* ob = reinterpret_cast<float*>(sb);    // P already consumed
#pragma unroll
  for (int it = 0; it < 2; ++it) {
    f32x4 o[8];
#pragma unroll
    for (int dt = 0; dt < 8; ++dt)
      o[dt] = __builtin_amdgcn_mfma_f32_16x16x32_bf16(va[dt], pa[it], (f32x4)0.0f, 0, 0, 0);
    // D[g*4+rr][c] = O[it*16+c][dt*16+g*4+rr] -> LDS row c (head), col d
#pragma unroll
    for (int dt = 0; dt < 8; ++dt)
      *reinterpret_cast<f32x4*>(&ob[c*OSTR + dt*16 + g*4]) = o[dt];
    // coalesced flush: 8 full-line nontemporal dwordx4 stores (write-once)
#pragma unroll
    for (int ch = 0; ch < 8; ++ch) {
      const int flat = 4*lane + 256*ch;        // 0..2047
      const int row = flat >> 7, col = flat & 127;
      f32x4 y = *reinterpret_cast<const f32x4*>(&ob[row*OSTR + col]);
      __builtin_nontemporal_store(y, reinterpret_cast<f32x4*>(op + it*2048 + flat));
    }
  }
}

extern "C" void kernel_launch(void* const* d_in, const int* in_sizes, int n_in,
                              void* d_out, int out_size, void* d_ws, size_t ws_size,
                              hipStream_t stream) {
  const float* q = (const float*)d_in[0];
  const float* k = (const float*)d_in[1];
  const float* v = (const float*)d_in[2];
  float* o = (float*)d_out;
  // 16384 positions (b=2 x s=8192), 4 waves/block -> 4096 blocks; 34816 B LDS
  hda<<<dim3(4096, 1, 1), dim3(256, 1, 1), 4 * BUFS * 2, stream>>>(q, k, v, o);
}

// Round 12
// 118.115 us; speedup vs baseline: 1.0414x; 1.0414x over previous
//
#include <hip/hip_runtime.h>
#include <hip/hip_bf16.h>

typedef __attribute__((ext_vector_type(4))) float f32x4;
typedef __attribute__((ext_vector_type(8))) __bf16 bf16x8;

#define NCTX 8192
#define DH 128
#define ROWE 4096                    /* floats between consecutive positions */
#define SC2 0.12751705766482797f     /* (1/sqrt(128)) * log2(e) */
#define KSTR 136                     /* bf16 row stride in staged buffers */
#define PSTR 40                      /* P lds row stride (shorts) */
#define OSTR 132                     /* O-bounce row stride (floats) */
#define BUFS (32*KSTR)               /* shorts per 8.5KB per-wave buffer */
#define NPRIV 1024                   /* private blocks: 4096 positions s<2048 */
#define NSHRD 768                    /* streaming blocks: 3072 waves x 128 rows */
#define ITERS 8                      /* 16-row tiles per streaming wave */

__device__ __forceinline__ unsigned f2bf(float x) {
  union { float f; unsigned u; } un; un.f = x;
  return (un.u + 0x7FFFu + ((un.u >> 16) & 1u)) >> 16;   // RNE f32->bf16 bits
}
__device__ __forceinline__ unsigned pk2(float a, float b) {
  float2 t; t.x = a; t.y = b;
  union { __hip_bfloat162 h; unsigned u; } un;
  un.h = __float22bfloat162_rn(t);
  return un.u;
}

// Stage one 4096-float global row -> LDS bf16 [32][KSTR], fully coalesced.
template<bool NT>
__device__ __forceinline__ void stage_row(const float* __restrict__ src,
                                          unsigned short* dst, int lane) {
  const int jb = lane >> 5, d = 4 * (lane & 31);
#pragma unroll
  for (int half = 0; half < 2; ++half) {
    f32x4 x[8];
#pragma unroll
    for (int ch = 0; ch < 8; ++ch) {
      const f32x4* p = reinterpret_cast<const f32x4*>(src + 4*lane + 256*(half*8 + ch));
      x[ch] = NT ? __builtin_nontemporal_load(p) : *p;
    }
#pragma unroll
    for (int ch = 0; ch < 8; ++ch) {
      const int j = jb + 2*(half*8 + ch);
      uint2 wv;
      wv.x = pk2(x[ch][0], x[ch][1]);
      wv.y = pk2(x[ch][2], x[ch][3]);
      *reinterpret_cast<uint2*>(&dst[j*KSTR + d]) = wv;
    }
  }
}

// V B-frag gather from a staged row buffer: va[dt] lane(c,g) = V[g*8+j][dt*16+c]
__device__ __forceinline__ void gather_va(const unsigned short* vbuf,
                                          bf16x8* va, int c, int g) {
#pragma unroll
  for (int dt = 0; dt < 8; ++dt) {
    unsigned t0 = vbuf[(g*8 + 0)*KSTR + dt*16 + c];
    unsigned t1 = vbuf[(g*8 + 1)*KSTR + dt*16 + c];
    unsigned t2 = vbuf[(g*8 + 2)*KSTR + dt*16 + c];
    unsigned t3 = vbuf[(g*8 + 3)*KSTR + dt*16 + c];
    unsigned t4 = vbuf[(g*8 + 4)*KSTR + dt*16 + c];
    unsigned t5 = vbuf[(g*8 + 5)*KSTR + dt*16 + c];
    unsigned t6 = vbuf[(g*8 + 6)*KSTR + dt*16 + c];
    unsigned t7 = vbuf[(g*8 + 7)*KSTR + dt*16 + c];
    union { unsigned u[4]; bf16x8 f; } un;
    un.u[0] = t0 | (t1 << 16); un.u[1] = t2 | (t3 << 16);
    un.u[2] = t4 | (t5 << 16); un.u[3] = t6 | (t7 << 16);
    va[dt] = un.f;
  }
}

// blocks [0,NPRIV): one wave per position s<2048 (distinct K/V row 4s) — R10 path.
// blocks [NPRIV,..): streaming GEMM over s>=2048 rows — K/V row 8191 in regs,
// 16 (pos,head)-rows per iteration, Q prefetched, coalesced NT in/out.
__global__ __launch_bounds__(256, 3) void hda(
    const float* __restrict__ q, const float* __restrict__ kg,
    const float* __restrict__ v, float* __restrict__ out)
{
  extern __shared__ __align__(16) unsigned short lds[];   // 4 bufs of BUFS shorts

  const int tid  = threadIdx.x;
  const int w    = tid >> 6;
  const int lane = tid & 63;
  const int c = lane & 15;
  const int g = lane >> 4;
  const int jb = lane >> 5, dcol = 4 * (lane & 31);

  unsigned short* sb = lds + w * BUFS;

  if (blockIdx.x < NPRIV) {
    // ================= private path (R10 verbatim, r = 4s exact) =================
    const int p = blockIdx.x * 4 + w;        // 0..4095
    const int b = p >> 11;
    const int s = p & 2047;
    const int r = 4 * s;

    const float* qsrc = q  + ((size_t)b * NCTX + s) * ROWE;
    const float* ksrc = kg + ((size_t)b * NCTX + r) * ROWE;
    const float* vsrc = v  + ((size_t)b * NCTX + r) * ROWE;
    float*       op   = out + ((size_t)b * NCTX + s) * ROWE;

    stage_row<true>(qsrc, sb, lane);
    bf16x8 qa[2][4];
#pragma unroll
    for (int t = 0; t < 2; ++t)
#pragma unroll
      for (int ks = 0; ks < 4; ++ks)
        qa[t][ks] = *reinterpret_cast<const bf16x8*>(&sb[(t*16 + c)*KSTR + ks*32 + g*8]);

    stage_row<false>(ksrc, sb, lane);
    bf16x8 kf[2][4];
#pragma unroll
    for (int t = 0; t < 2; ++t)
#pragma unroll
      for (int ks = 0; ks < 4; ++ks)
        kf[t][ks] = *reinterpret_cast<const bf16x8*>(&sb[(t*16 + c)*KSTR + ks*32 + g*8]);

    f32x4 vx[8];
#pragma unroll
    for (int ch = 0; ch < 8; ++ch)
      vx[ch] = *reinterpret_cast<const f32x4*>(vsrc + 4*lane + 256*ch);
    __builtin_amdgcn_sched_barrier(0);

    f32x4 S[2][2];
#pragma unroll
    for (int it = 0; it < 2; ++it)
#pragma unroll
      for (int jt = 0; jt < 2; ++jt) {
        f32x4 acc = (f32x4)0.0f;
#pragma unroll
        for (int ks = 0; ks < 4; ++ks)
          acc = __builtin_amdgcn_mfma_f32_16x16x32_bf16(qa[it][ks], kf[jt][ks], acc, 0, 0, 0);
        S[it][jt] = acc;
      }

#pragma unroll
    for (int ch = 0; ch < 8; ++ch) {
      uint2 wv;
      wv.x = pk2(vx[ch][0], vx[ch][1]);
      wv.y = pk2(vx[ch][2], vx[ch][3]);
      *reinterpret_cast<uint2*>(&sb[(jb + 2*ch)*KSTR + dcol]) = wv;
    }
#pragma unroll
    for (int ch = 0; ch < 8; ++ch)
      vx[ch] = *reinterpret_cast<const f32x4*>(vsrc + 4*lane + 256*(8 + ch));
    __builtin_amdgcn_sched_barrier(0);

    float pp[2][2][4], inv[2][4];
#pragma unroll
    for (int it = 0; it < 2; ++it) {
      float ls[4] = {0.f, 0.f, 0.f, 0.f};
#pragma unroll
      for (int jt = 0; jt < 2; ++jt)
#pragma unroll
        for (int rr = 0; rr < 4; ++rr) {
          float e = exp2f(S[it][jt][rr] * SC2);
          pp[it][jt][rr] = e;
          ls[rr] += e;
        }
#pragma unroll
      for (int m = 1; m <= 8; m <<= 1)
#pragma unroll
        for (int rr = 0; rr < 4; ++rr)
          ls[rr] += __shfl_xor(ls[rr], m);
#pragma unroll
      for (int rr = 0; rr < 4; ++rr) inv[it][rr] = 1.0f / ls[rr];
    }

#pragma unroll
    for (int ch = 0; ch < 8; ++ch) {
      uint2 wv;
      wv.x = pk2(vx[ch][0], vx[ch][1]);
      wv.y = pk2(vx[ch][2], vx[ch][3]);
      *reinterpret_cast<uint2*>(&sb[(jb + 2*(8 + ch))*KSTR + dcol]) = wv;
    }

    bf16x8 va[8];
    gather_va(sb, va, c, g);

#pragma unroll
    for (int it = 0; it < 2; ++it)
#pragma unroll
      for (int jt = 0; jt < 2; ++jt)
#pragma unroll
        for (int rr = 0; rr < 4; ++rr)
          sb[(it*16 + g*4 + rr)*PSTR + jt*16 + c] =
              (unsigned short)f2bf(pp[it][jt][rr] * inv[it][rr]);

    bf16x8 pa[2];
    pa[0] = *reinterpret_cast<const bf16x8*>(&sb[c*PSTR + g*8]);
    pa[1] = *reinterpret_cast<const bf16x8*>(&sb[(16 + c)*PSTR + g*8]);

    float* ob = reinterpret_cast<float*>(sb);
#pragma unroll
    for (int it = 0; it < 2; ++it) {
      f32x4 o[8];
#pragma unroll
      for (int dt = 0; dt < 8; ++dt)
        o[dt] = __builtin_amdgcn_mfma_f32_16x16x32_bf16(va[dt], pa[it], (f32x4)0.0f, 0, 0, 0);
#pragma unroll
      for (int dt = 0; dt < 8; ++dt)
        *reinterpret_cast<f32x4*>(&ob[c*OSTR + dt*16 + g*4]) = o[dt];
#pragma unroll
      for (int ch = 0; ch < 8; ++ch) {
        const int flat = 4*lane + 256*ch;
        const int row = flat >> 7, col = flat & 127;
        f32x4 y = *reinterpret_cast<const f32x4*>(&ob[row*OSTR + col]);
        __builtin_nontemporal_store(y, reinterpret_cast<f32x4*>(op + it*2048 + flat));
      }
    }
    return;
  }

  // ================= streaming path: s >= 2048, shared K/V row 8191 =================
  const int gw = (blockIdx.x - NPRIV) * 4 + w;      // 0..3071
  const int b  = (gw >= 1536) ? 1 : 0;
  const size_t frbase = (size_t)(gw - b*1536) * 128;  // first (pos,head) row
  const float* qbase = q   + ((size_t)b*262144 + 65536 + frbase) * DH;
  float*       obase = out + ((size_t)b*262144 + 65536 + frbase) * DH;
  const float* k8 = kg + ((size_t)b * NCTX + (NCTX-1)) * ROWE;
  const float* v8 = v  + ((size_t)b * NCTX + (NCTX-1)) * ROWE;

  // K8191 -> register B-frags (once)
  stage_row<false>(k8, sb, lane);
  bf16x8 kf[2][4];
#pragma unroll
  for (int t = 0; t < 2; ++t)
#pragma unroll
    for (int ks = 0; ks < 4; ++ks)
      kf[t][ks] = *reinterpret_cast<const bf16x8*>(&sb[(t*16 + c)*KSTR + ks*32 + g*8]);

  // V8191 -> register frags via one-time gather
  stage_row<false>(v8, sb, lane);
  bf16x8 va[8];
  gather_va(sb, va, c, g);

  // Q prologue: stage rows 0..15 (2048 floats, coalesced NT)
  {
    f32x4 x[8];
#pragma unroll
    for (int ch = 0; ch < 8; ++ch)
      x[ch] = __builtin_nontemporal_load(
          reinterpret_cast<const f32x4*>(qbase + 4*lane + 256*ch));
#pragma unroll
    for (int ch = 0; ch < 8; ++ch) {
      uint2 wv;
      wv.x = pk2(x[ch][0], x[ch][1]);
      wv.y = pk2(x[ch][2], x[ch][3]);
      *reinterpret_cast<uint2*>(&sb[(jb + 2*ch)*KSTR + dcol]) = wv;
    }
  }

  f32x4 pf[8];
#pragma unroll 1
  for (int iter = 0; iter < ITERS; ++iter) {
    // Q A-frags for this 16-row tile
    bf16x8 qa[4];
#pragma unroll
    for (int ks = 0; ks < 4; ++ks)
      qa[ks] = *reinterpret_cast<const bf16x8*>(&sb[c*KSTR + ks*32 + g*8]);

    // prefetch next tile's Q (latency hides under MFMA/softmax/PV below)
    if (iter + 1 < ITERS) {
#pragma unroll
      for (int ch = 0; ch < 8; ++ch)
        pf[ch] = __builtin_nontemporal_load(reinterpret_cast<const f32x4*>(
            qbase + (size_t)(iter + 1) * 2048 + 4*lane + 256*ch));
      __builtin_amdgcn_sched_barrier(0);
    }

    // S = Q K^T : 2 jt tiles, K-dim 128
    f32x4 S[2];
#pragma unroll
    for (int jt = 0; jt < 2; ++jt) {
      f32x4 acc = (f32x4)0.0f;
#pragma unroll
      for (int ks = 0; ks < 4; ++ks)
        acc = __builtin_amdgcn_mfma_f32_16x16x32_bf16(qa[ks], kf[jt][ks], acc, 0, 0, 0);
      S[jt] = acc;
    }

    // softmax over 32 cols; rows = g*4+rr
    float pp[2][4], ls[4] = {0.f, 0.f, 0.f, 0.f};
#pragma unroll
    for (int jt = 0; jt < 2; ++jt)
#pragma unroll
      for (int rr = 0; rr < 4; ++rr) {
        float e = exp2f(S[jt][rr] * SC2);
        pp[jt][rr] = e;
        ls[rr] += e;
      }
#pragma unroll
    for (int m = 1; m <= 8; m <<= 1)
#pragma unroll
      for (int rr = 0; rr < 4; ++rr)
        ls[rr] += __shfl_xor(ls[rr], m);
    float inv[4];
#pragma unroll
    for (int rr = 0; rr < 4; ++rr) inv[rr] = 1.0f / ls[rr];

    // P -> LDS, read back as A-frag
#pragma unroll
    for (int jt = 0; jt < 2; ++jt)
#pragma unroll
      for (int rr = 0; rr < 4; ++rr)
        sb[(g*4 + rr)*PSTR + jt*16 + c] =
            (unsigned short)f2bf(pp[jt][rr] * inv[rr]);
    bf16x8 pa = *reinterpret_cast<const bf16x8*>(&sb[c*PSTR + g*8]);

    // O^T = V^T P^T : 8 dt tiles; bounce + coalesced NT stores
    f32x4 o[8];
#pragma unroll
    for (int dt = 0; dt < 8; ++dt)
      o[dt] = __builtin_amdgcn_mfma_f32_16x16x32_bf16(va[dt], pa, (f32x4)0.0f, 0, 0, 0);
    float* ob = reinterpret_cast<float*>(sb);
#pragma unroll
    for (int dt = 0; dt < 8; ++dt)
      *reinterpret_cast<f32x4*>(&ob[c*OSTR + dt*16 + g*4]) = o[dt];
#pragma unroll
    for (int ch = 0; ch < 8; ++ch) {
      const int flat = 4*lane + 256*ch;
      const int row = flat >> 7, col = flat & 127;
      f32x4 y = *reinterpret_cast<const f32x4*>(&ob[row*OSTR + col]);
      __builtin_nontemporal_store(y, reinterpret_cast<f32x4*>(
          obase + (size_t)iter * 2048 + flat));
    }

    // write prefetched Q over sb (after O flush reads)
    if (iter + 1 < ITERS) {
#pragma unroll
      for (int ch = 0; ch < 8; ++ch) {
        uint2 wv;
        wv.x = pk2(pf[ch][0], pf[ch][1]);
        wv.y = pk2(pf[ch][2], pf[ch][3]);
        *reinterpret_cast<uint2*>(&sb[(jb + 2*ch)*KSTR + dcol]) = wv;
      }
    }
  }
}

extern "C" void kernel_launch(void* const* d_in, const int* in_sizes, int n_in,
                              void* d_out, int out_size, void* d_ws, size_t ws_size,
                              hipStream_t stream) {
  const float* q = (const float*)d_in[0];
  const float* k = (const float*)d_in[1];
  const float* v = (const float*)d_in[2];
  float* o = (float*)d_out;
  // 1024 private blocks (4096 positions s<2048) + 768 streaming blocks
  // (3072 waves x 128 (pos,head)-rows of s>=2048); 34816 B LDS
  hda<<<dim3(NPRIV + NSHRD, 1, 1), dim3(256, 1, 1), 4 * BUFS * 2, stream>>>(q, k, v, o);
}